// Round 13
// baseline (350.339 us; speedup 1.0000x reference)
//
#include <hip/hip_runtime.h>
#include <stdint.h>

// RGCN round 22. Base = r21 champion (341.9us). ONE change: gemm edge-QUAD
// merge (grid 1280 -> 768 per layer). Each g0 had 5 blocks (self-pair + 4
// edge-pairs); now self-pair + 2 edge-quads. A quad covers 4 W tiles
// (e_i,e_i+1 x o0/o64 -- contiguous in wp_edge), staged as 8 HALF-tiles
// through a 4-slot LDS ring with counted vmcnt (the r21-spmm discipline
// applied to gemm W). H staged once per quad (was once per pair). Per-tile
// kk order preserved (half h = kk 2h,2h+1) -> bit-identical, absmax
// 0.03125. LDS unchanged (50KB, 3 blocks/CU). Self path + spmm + bnstat +
// pack/prep byte-identical to r21.

typedef float  f32x4  __attribute__((ext_vector_type(4)));
typedef __bf16 bf16x8 __attribute__((ext_vector_type(8)));
typedef __bf16 bf16x4 __attribute__((ext_vector_type(4)));
typedef unsigned short ushort8v __attribute__((ext_vector_type(8)));
typedef uint32_t uint4v __attribute__((ext_vector_type(4)));

#define MBATCH 32
#define ETYPES 4
#define NNODE  512
#define HIDD   128

#define GLB(p) (const __attribute__((address_space(1))) uint32_t*)(p)
#define LDSp(p) (__attribute__((address_space(3))) uint32_t*)(p)

// packed-weight pool offsets (elements)
#define WP_S0 0
#define WP_E0 8192
#define WP_S1 40960
#define WP_E1 57344
#define WP_S2 122880
#define WP_E2 139264
#define WP_W1 204800
#define WP_W2 221184

struct Params {
  const float* x;
  const float* adj;
  const float* wself[3]; const float* bself[3];
  const float* wedge[3]; const float* bedge[3];
  const float* bng[3];   const float* bnb[3];
  const float* w1; const float* b1;
  const float* bnfg; const float* bnfb;
  const float* w2; const float* b2;
  __bf16* mmp; __bf16* hs; __bf16* part;
  __bf16* hb0; __bf16* hb1;
  uint32_t* bm; float* degp; __bf16* wp;
  float* out;
};

// ---------------- phase: pack (r9-proven ballot body) ----------------
__device__ void pack_phase(const float* __restrict__ adj, uint32_t* __restrict__ bm,
                           float* __restrict__ degp, int bid, int t, int nbl) {
  int wave = t >> 6, lane = t & 63;
  for (int rg = bid; rg < 16384; rg += nbl) {
    int r = rg * 4 + wave;                  // 65536 rows (b,e,n)
    int b = r >> 11, e = (r >> 9) & 3, n = r & 511;
    const float* row = adj + (long)r * 512;
    uint32_t myw = 0;
#pragma unroll
    for (int i = 0; i < 8; ++i) {
      uint64_t bal = __ballot(row[i * 64 + lane] != 0.f);
      uint32_t lo = (uint32_t)bal, hi = (uint32_t)(bal >> 32);
      if ((lane >> 1) == i) myw = (lane & 1) ? hi : lo;
    }
    if (lane == (n >> 5)) myw &= ~(1u << (n & 31));   // zero diagonal
    int pc = (lane < 16) ? __popc(myw) : 0;
    pc += __shfl_down(pc, 8);
    pc += __shfl_down(pc, 4);
    pc += __shfl_down(pc, 2);
    pc += __shfl_down(pc, 1);
    if (lane < 16) bm[(long)r * 16 + lane] = myw;
    if (lane == 0) degp[e * 16384 + b * 512 + n] = (float)pc;
  }
}

// ---------------- phase: prep (r9-proven body) ----------------
__device__ void prep_phase(const Params& P, int bid, int t, int nbl) {
  const float* Ws[8] = {P.wself[0], P.wedge[0], P.wself[1], P.wedge[1],
                        P.wself[2], P.wedge[2], P.w1, P.w2};
  const int Kt[8]  = {64, 64, 128, 128, 128, 128, 128, 128};
  const int NB[8]  = {2, 8, 2, 8, 2, 8, 2, 2};
  const int OFF[8] = {WP_S0, WP_E0, WP_S1, WP_E1, WP_S2, WP_E2, WP_W1, WP_W2};
#pragma unroll
  for (int wid = 0; wid < 8; ++wid) {
    int K = Kt[wid], nblk = NB[wid];
    int tot = K * nblk * 64;
    for (int gid = bid * 256 + t; gid < tot; gid += nbl * 256) {
      int c = gid & 63;
      int k = (gid >> 6) % K;
      int blk = (gid >> 6) / K;
      int edge = (nblk == 8);
      int WS = edge ? 512 : 128;
      int col = edge ? (((blk & 1) * 64 + c) * 4 + (blk >> 1)) : (blk * 64 + c);
      P.wp[OFF[wid] + (long)blk * K * 64 + (k >> 3) * 512 + c * 8 + (k & 7)] =
          (__bf16)Ws[wid][k * WS + col];
    }
  }
}

// ---------------- phase: gemm (r22: self-pair + edge-quad w/ half-tile ring) ----
// block pr: 0 = self pair (by 0,1; r19-proven path, Wl0/Wl1 on ring slots);
// 1,2 = edge quad eq=pr-1: tiles j=0..3 -> e=eq*2+(j>>1), o0=(j&1)*64, W
// blocks eq*4+j contiguous in wp_edge. Quad stages 8 half-tiles (K*64 B)
// through 4-slot ring; half h of tile j = kk {2h,2h+1} (K=128) / kk h
// (K=64) -> per-tile accumulation order identical to pair version.
template <int K, bool F32IN, bool F32OUT>
__device__ void gemm_phase(char* smem, const void* __restrict__ hv,
                           const __bf16* __restrict__ wp_self,
                           const float* __restrict__ bias_self,
                           const __bf16* __restrict__ wp_edge,
                           const float* __restrict__ bias_edge,
                           const float* __restrict__ degp,
                           float* __restrict__ outF, __bf16* __restrict__ outB,
                           __bf16* __restrict__ mmp,
                           int nblocks, int bid, int t, int nbl) {
  __bf16 (*Hl)[K + 8] = (__bf16(*)[K + 8])smem;
  __bf16* Wring = (__bf16*)(smem + 64 * (K + 8) * 2);  // 4 slots x K*64 bytes
  __bf16* Wl0 = Wring;                 // self path: tile = 2 slots
  __bf16* Wl1 = Wring + K * 64;        // elements (= 2 slots)
  constexpr int HI = K / 32;           // H chunks per thread
  constexpr int W = K / 64;            // gload_lds per wave per half-tile
  int wave = t >> 6, lane = t & 63, l15 = lane & 15, q = lane >> 4;
  for (int blki = bid; blki < nblocks; blki += nbl) {
    __syncthreads();                   // smem free from prev block
    int g0 = (blki & 255) * 64;
    int pr = blki >> 8;
    // --- H loads first (vmcnt retires in issue order: keeps W countable) ---
    f32x4 ha[F32IN ? HI : 1], hb4[F32IN ? HI : 1];
    bf16x8 hr[F32IN ? 1 : HI];
#pragma unroll
    for (int ii = 0; ii < HI; ++ii) {
      int idx = t + ii * 256;
      int r = idx / (K / 8), ch = idx % (K / 8);
      if (F32IN) {
        const float* xf = (const float*)hv;
        ha[ii]  = *(const f32x4*)(xf + (long)(g0 + r) * K + ch * 8);
        hb4[ii] = *(const f32x4*)(xf + (long)(g0 + r) * K + ch * 8 + 4);
      } else {
        const __bf16* hbp = (const __bf16*)hv;
        hr[ii] = *(const bf16x8*)(hbp + (long)(g0 + r) * K + ch * 8);
      }
    }
    __builtin_amdgcn_sched_barrier(0);

    if (pr == 0) {
      // ---------------- self pair (r19-proven) ----------------
      {
        const char* g1 = (const char*)wp_self;
        const char* g2 = (const char*)(wp_self + (long)K * 64);
#pragma unroll
        for (int i = 0; i < K / 32; ++i)
          __builtin_amdgcn_global_load_lds(GLB(g1 + i * 4096 + wave * 1024 + lane * 16),
                                           LDSp((char*)Wl0 + i * 4096 + wave * 1024),
                                           16, 0, 0);
#pragma unroll
        for (int i = 0; i < K / 32; ++i)
          __builtin_amdgcn_global_load_lds(GLB(g2 + i * 4096 + wave * 1024 + lane * 16),
                                           LDSp((char*)Wl1 + i * 4096 + wave * 1024),
                                           16, 0, 0);
      }
      __builtin_amdgcn_sched_barrier(0);
#pragma unroll
      for (int ii = 0; ii < HI; ++ii) {
        int idx = t + ii * 256;
        int r = idx / (K / 8), ch = idx % (K / 8);
        if (F32IN) {
          bf16x8 o;
#pragma unroll
          for (int j = 0; j < 4; ++j) { o[j] = (__bf16)ha[ii][j]; o[4 + j] = (__bf16)hb4[ii][j]; }
          *(bf16x8*)&Hl[r][ch * 8] = o;
        } else {
          *(bf16x8*)&Hl[r][ch * 8] = hr[ii];
        }
      }
      asm volatile("s_waitcnt lgkmcnt(0)" ::: "memory");
      if (K == 128) asm volatile("s_waitcnt vmcnt(4)" ::: "memory");
      else          asm volatile("s_waitcnt vmcnt(2)" ::: "memory");
      __builtin_amdgcn_s_barrier();
      asm volatile("" ::: "memory");
      f32x4 acc1[4] = {}, acc2[4] = {};
#pragma unroll
      for (int kk = 0; kk < K / 32; ++kk) {
        bf16x8 af = *(const bf16x8*)&Hl[wave * 16 + l15][kk * 32 + q * 8];
#pragma unroll
        for (int c = 0; c < 4; ++c) {
          bf16x8 bfr = *(const bf16x8*)&Wl0[((kk * 4 + q) * 64 + c * 16 + l15) * 8];
          acc1[c] = __builtin_amdgcn_mfma_f32_16x16x32_bf16(af, bfr, acc1[c], 0, 0, 0);
        }
      }
      asm volatile("s_waitcnt vmcnt(0)" ::: "memory");
      __builtin_amdgcn_s_barrier();
      asm volatile("" ::: "memory");
#pragma unroll
      for (int kk = 0; kk < K / 32; ++kk) {
        bf16x8 af = *(const bf16x8*)&Hl[wave * 16 + l15][kk * 32 + q * 8];
#pragma unroll
        for (int c = 0; c < 4; ++c) {
          bf16x8 bfr = *(const bf16x8*)&Wl1[((kk * 4 + q) * 64 + c * 16 + l15) * 8];
          acc2[c] = __builtin_amdgcn_mfma_f32_16x16x32_bf16(af, bfr, acc2[c], 0, 0, 0);
        }
      }
#pragma unroll
      for (int h = 0; h < 2; ++h) {
        f32x4* acc = h ? acc2 : acc1;
        int c0 = h * 64;
#pragma unroll
        for (int c = 0; c < 4; ++c) {
          float bc = bias_self[c0 + c * 16 + l15];
#pragma unroll
          for (int i = 0; i < 4; ++i) {
            int g = g0 + wave * 16 + q * 4 + i;
            if (F32OUT)
              outF[(long)g * HIDD + c0 + c * 16 + l15] = acc[c][i] + bc;
            else
              outB[(long)g * HIDD + c0 + c * 16 + l15] = (__bf16)(acc[c][i] + bc);
          }
        }
      }
    } else {
      // ---------------- edge quad (r22: 8 half-tiles, 4-slot ring) ----------------
      int eq = pr - 1;
      const char* wbase = (const char*)(wp_edge + (long)eq * 4 * K * 64);
      auto wstage = [&](int s) {
        char* dst = (char*)Wring + (s & 3) * (K * 64);
#pragma unroll
        for (int w2 = 0; w2 < W; ++w2)
          __builtin_amdgcn_global_load_lds(
              GLB(wbase + (long)s * (K * 64) + (wave * W + w2) * 1024 + lane * 16),
              LDSp(dst + (wave * W + w2) * 1024), 16, 0, 0);
      };
      wstage(0); wstage(1); wstage(2);
      __builtin_amdgcn_sched_barrier(0);
#pragma unroll
      for (int ii = 0; ii < HI; ++ii) {
        int idx = t + ii * 256;
        int r = idx / (K / 8), ch = idx % (K / 8);
        if (F32IN) {
          bf16x8 o;
#pragma unroll
          for (int j = 0; j < 4; ++j) { o[j] = (__bf16)ha[ii][j]; o[4 + j] = (__bf16)hb4[ii][j]; }
          *(bf16x8*)&Hl[r][ch * 8] = o;
        } else {
          *(bf16x8*)&Hl[r][ch * 8] = hr[ii];
        }
      }
      asm volatile("s_waitcnt lgkmcnt(0)" ::: "memory");   // H in LDS
      if (K == 128) asm volatile("s_waitcnt vmcnt(4)" ::: "memory");  // half0 done
      else          asm volatile("s_waitcnt vmcnt(2)" ::: "memory");
      __builtin_amdgcn_s_barrier();
      asm volatile("" ::: "memory");
      f32x4 acc[4][4] = {};
#pragma unroll
      for (int s = 0; s < 8; ++s) {
        if (s < 5) wstage(s + 3);       // ring[(s+3)&3]: consumed at s-1, safe
        int j = s >> 1, h = s & 1;
        const char* slot = (const char*)Wring + (s & 3) * (K * 64);
#pragma unroll
        for (int z = 0; z < K / 64; ++z) {
          int kk = h * (K / 64) + z;
          bf16x8 af = *(const bf16x8*)&Hl[wave * 16 + l15][kk * 32 + q * 8];
#pragma unroll
          for (int c = 0; c < 4; ++c) {
            bf16x8 bfr = *(const bf16x8*)(slot + (4 * z + q) * 1024 + (c * 16 + l15) * 16);
            acc[j][c] = __builtin_amdgcn_mfma_f32_16x16x32_bf16(af, bfr, acc[j][c], 0, 0, 0);
          }
        }
        if (s < 7) {
          // wait half s+1 (oldest needed); leave later halves in flight
          if (s < 5) {
            if (K == 128) asm volatile("s_waitcnt vmcnt(4)" ::: "memory");
            else          asm volatile("s_waitcnt vmcnt(2)" ::: "memory");
          } else if (s == 5) {
            if (K == 128) asm volatile("s_waitcnt vmcnt(2)" ::: "memory");
            else          asm volatile("s_waitcnt vmcnt(1)" ::: "memory");
          } else {
            asm volatile("s_waitcnt vmcnt(0)" ::: "memory");
          }
          __builtin_amdgcn_s_barrier();
          asm volatile("" ::: "memory");
        }
      }
      // epilogue: 4 edge tiles; iv shared across the quad
      float iv[4];
#pragma unroll
      for (int i = 0; i < 4; ++i) {
        int gg = g0 + wave * 16 + q * 4 + i;
        float d = degp[gg] + degp[16384 + gg] + degp[32768 + gg] + degp[49152 + gg];
        iv[i] = d > 0.f ? 1.f / d : 0.f;       // bit-identical to k_inv
      }
      int octg = ((g0 & 511) >> 3) + wave * 2 + (q >> 1);
      int j0   = (q & 1) * 4;
#pragma unroll
      for (int j = 0; j < 4; ++j) {
        int e = eq * 2 + (j >> 1);
        int o0 = (j & 1) * 64;
        int b4e = (g0 >> 9) * 4 + e;
#pragma unroll
        for (int c = 0; c < 4; ++c) {
          int o = o0 + c * 16 + l15;
          float bc = bias_edge[o * 4 + e];
          bf16x4 v4;
#pragma unroll
          for (int i = 0; i < 4; ++i) v4[i] = (__bf16)((acc[j][c][i] + bc) * iv[i]);
          *(bf16x4*)(mmp + ((long)(b4e * 64 + octg) * HIDD + o) * 8 + j0) = v4;
        }
      }
    }
  }
}

// ---------------- phase: spmm (r21-proven: oc-merged, 4-deep ring) ----------------
__device__ void spmm_phase(char* smem, const uint32_t* __restrict__ bm,
                           const __bf16* __restrict__ mmp,
                           __bf16* __restrict__ part, int bid, int t) {
  int wave = t >> 6, lane = t & 63, l15 = lane & 15, q = lane >> 4;
  int nt = bid >> 7;                    // 0..3
  int eb = bid & 127;                   // e*32 + b
  int e = eb >> 5, b = eb & 31;
  int n0 = nt * 128;

  const uint32_t* bmr = bm + ((long)((b * 4 + e) * 512 + n0 + wave * 32 + l15)) * 16;
  uint32_t rm0[16], rm1[16];
#pragma unroll
  for (int i = 0; i < 4; ++i) {
    uint4v v0 = *(const uint4v*)(bmr + i * 4);
    uint4v v1 = *(const uint4v*)(bmr + 256 + i * 4);   // +16 rows * 16 words
    rm0[i * 4 + 0] = v0.x; rm0[i * 4 + 1] = v0.y; rm0[i * 4 + 2] = v0.z; rm0[i * 4 + 3] = v0.w;
    rm1[i * 4 + 0] = v1.x; rm1[i * 4 + 1] = v1.y; rm1[i * 4 + 2] = v1.z; rm1[i * 4 + 3] = v1.w;
  }

  // per-wave stage of phase mc: 2 octets x 2 halves (1 KB each), linear dest
  auto stage = [&](int mc, char* dst) {
#pragma unroll
    for (int i = 0; i < 2; ++i) {
      int oct = wave * 2 + i;
#pragma unroll
      for (int hf = 0; hf < 2; ++hf) {
        const char* g = (const char*)mmp +
            ((long)(b * 4 + e) * 65536 + mc * 8192 + oct * 1024 + hf * 512) * 2;
        __builtin_amdgcn_global_load_lds(GLB(g + lane * 16),
                                         LDSp(dst + oct * 2048 + hf * 1024), 16, 0, 0);
      }
    }
  };

  stage(0, smem);                      // prologue: 3 phases in flight (12 loads)
  stage(1, smem + 16384);
  stage(2, smem + 32768);

  f32x4 acc0[8] = {}, acc1[8] = {};
#pragma unroll
  for (int mc = 0; mc < 8; ++mc) {
    // wait for phase mc's 4 loads (oldest); leave later phases in flight
    if (mc <= 5)      asm volatile("s_waitcnt vmcnt(8)" ::: "memory");
    else if (mc == 6) asm volatile("s_waitcnt vmcnt(4)" ::: "memory");
    else              asm volatile("s_waitcnt vmcnt(0)" ::: "memory");
    __builtin_amdgcn_s_barrier();
    asm volatile("" ::: "memory");
    if (mc < 5) stage(mc + 3, smem + ((mc + 3) & 3) * 16384);
    const __bf16* Bl = (const __bf16*)(smem + (mc & 3) * 16384);
#pragma unroll
    for (int kk = 0; kk < 2; ++kk) {
      uint32_t bits0 = (rm0[mc * 2 + kk] >> (q * 8)) & 0xffu;
      uint32_t bits1 = (rm1[mc * 2 + kk] >> (q * 8)) & 0xffu;
      ushort8v a0, a1;
#pragma unroll
      for (int j = 0; j < 8; ++j) {
        a0[j] = (bits0 >> j & 1u) ? (unsigned short)0x3F80 : (unsigned short)0;
        a1[j] = (bits1 >> j & 1u) ? (unsigned short)0x3F80 : (unsigned short)0;
      }
      union { ushort8v u; bf16x8 v; } c0, c1; c0.u = a0; c1.u = a1;
#pragma unroll
      for (int c = 0; c < 8; ++c) {
        bf16x8 bfr = *(const bf16x8*)&Bl[((kk * 4 + q) * 128 + c * 16 + l15) * 8];
        acc0[c] = __builtin_amdgcn_mfma_f32_16x16x32_bf16(c0.v, bfr, acc0[c], 0, 0, 0);
        acc1[c] = __builtin_amdgcn_mfma_f32_16x16x32_bf16(c1.v, bfr, acc1[c], 0, 0, 0);
      }
    }
  }

  __bf16* dst = part + (long)(e * 32 + b) * NNODE * HIDD;
#pragma unroll
  for (int c = 0; c < 8; ++c) {
#pragma unroll
    for (int i = 0; i < 4; ++i) {
      int n = n0 + wave * 32 + q * 4 + i;
      int o = c * 16 + l15;
      dst[(long)n * HIDD + o] = (__bf16)acc0[c][i];
      dst[(long)(n + 16) * HIDD + o] = (__bf16)acc1[c][i];
    }
  }
}

// ---------------- phase: bnstat (r20-proven: one wave per n, barrier-free) --------
template <bool HASP>
__global__ __launch_bounds__(64) void g_bnstat(const __bf16* __restrict__ hs,
                                               const __bf16* __restrict__ part,
                                               const float* __restrict__ gg,
                                               const float* __restrict__ bb,
                                               __bf16* __restrict__ hb) {
  int n = blockIdx.x;                  // one n per wave
  int lane = threadIdx.x;
  int o4 = lane & 31;                  // o-chunk index (4 elems)
  int bq = lane >> 5;                  // 0/1
  f32x4 v[16];
  float s = 0.f, sq = 0.f;
#pragma unroll
  for (int i = 0; i < 16; ++i) {
    int b = bq + i * 2;
    long base = ((long)b * NNODE + n) * HIDD + o4 * 4;
    bf16x4 hv = *(const bf16x4*)(hs + base);
    f32x4 t;
#pragma unroll
    for (int j = 0; j < 4; ++j) t[j] = (float)hv[j];
    if (HASP) {
#pragma unroll
      for (int e = 0; e < 4; ++e) {
        bf16x4 pv = *(const bf16x4*)(part + ((long)(e * 32 + b) * NNODE + n) * HIDD + o4 * 4);
#pragma unroll
        for (int j = 0; j < 4; ++j) t[j] += (float)pv[j];
      }
    }
    v[i] = t;
#pragma unroll
    for (int j = 0; j < 4; ++j) { s += t[j]; sq += t[j] * t[j]; }
  }
#pragma unroll
  for (int off = 1; off < 64; off <<= 1) {
    s  += __shfl_xor(s, off);
    sq += __shfl_xor(sq, off);
  }
  float mean = s * (1.f / 4096.f);
  float var = sq * (1.f / 4096.f) - mean * mean;   // biased, torch BN1d
  float rstd = rsqrtf(var + 1e-5f);
  float sc = gg[n] * rstd;
  float sh = bb[n] - mean * sc;
#pragma unroll
  for (int i = 0; i < 16; ++i) {
    int b = bq + i * 2;
    bf16x4 o;
#pragma unroll
    for (int j = 0; j < 4; ++j) {
      float x = v[i][j] * sc + sh;
      o[j] = (__bf16)(x > 0.f ? x : 0.f);
    }
    *(bf16x4*)(hb + ((long)b * NNODE + n) * HIDD + o4 * 4) = o;
  }
}

// ---------------- kernels ----------------
__global__ __launch_bounds__(256) void g_packprep(Params P) {
  pack_phase(P.adj, P.bm, P.degp, blockIdx.x, threadIdx.x, gridDim.x);
  prep_phase(P, blockIdx.x, threadIdx.x, gridDim.x);
}
template <int K, bool F32IN, bool F32OUT>
__global__ __launch_bounds__(256) void g_gemm(const void* hv, const __bf16* wps,
                                              const float* bs, const __bf16* wpe,
                                              const float* be, const float* degp,
                                              float* outF, __bf16* outB,
                                              __bf16* mmp, int nblocks) {
  __shared__ __align__(16) char smem[64 * (K + 8) * 2 + 4 * K * 64];
  gemm_phase<K, F32IN, F32OUT>(smem, hv, wps, bs, wpe, be, degp, outF, outB,
                               mmp, nblocks, blockIdx.x, threadIdx.x, gridDim.x);
}
__global__ __launch_bounds__(256) void g_spmm(const uint32_t* bm, const __bf16* mmp,
                                              __bf16* part) {
  __shared__ __align__(16) char smem[65536];
  spmm_phase(smem, bm, mmp, part, blockIdx.x, threadIdx.x);
}

extern "C" void kernel_launch(void* const* d_in, const int* in_sizes, int n_in,
                              void* d_out, int out_size, void* d_ws, size_t ws_size,
                              hipStream_t stream) {
  (void)in_sizes; (void)n_in; (void)out_size; (void)ws_size;
  Params P;
  P.x   = (const float*)d_in[0];
  P.adj = (const float*)d_in[1];
  for (int l = 0; l < 3; ++l) {
    P.wself[l] = (const float*)d_in[2 + 6 * l];
    P.bself[l] = (const float*)d_in[3 + 6 * l];
    P.wedge[l] = (const float*)d_in[4 + 6 * l];
    P.bedge[l] = (const float*)d_in[5 + 6 * l];
    P.bng[l]   = (const float*)d_in[6 + 6 * l];
    P.bnb[l]   = (const float*)d_in[7 + 6 * l];
  }
  P.w1   = (const float*)d_in[20];
  P.b1   = (const float*)d_in[21];
  P.bnfg = (const float*)d_in[22];
  P.bnfb = (const float*)d_in[23];
  P.w2   = (const float*)d_in[24];
  P.b2   = (const float*)d_in[25];

  char* ws = (char*)d_ws;
  P.mmp  = (__bf16*)ws;                  // 16,777,216
  P.hs   = (__bf16*)(ws + 16777216);     //  4,194,304 used (slot 8 MB, bf16)
  P.part = (__bf16*)(ws + 25165824);     // 16,777,216 (bf16)
  P.hb0  = (__bf16*)(ws + 41943040);     //  4,194,304
  P.hb1  = (__bf16*)(ws + 46137344);     //  4,194,304
  P.bm   = (uint32_t*)(ws + 50331648);   //  4,194,304
  P.degp = (float*)(ws + 54525952);      //    262,144
  P.wp   = (__bf16*)(ws + 54788096);     //    475,136 -> ~55.3 MB total
  P.out  = (float*)d_out;

  g_packprep<<<16384, 256, 0, stream>>>(P);

  // layer 0 (K=64, fp32 input x): 768 blocks (256 self-pair + 512 edge-quad)
  g_gemm<64, true, false><<<768, 256, 0, stream>>>(P.x, P.wp + WP_S0, P.bself[0],
      P.wp + WP_E0, P.bedge[0], P.degp, nullptr, P.hs, P.mmp, 768);
  g_spmm<<<512, 256, 0, stream>>>(P.bm, P.mmp, P.part);
  g_bnstat<true><<<512, 64, 0, stream>>>(P.hs, P.part, P.bng[0], P.bnb[0], P.hb0);

  // layer 1 (K=128)
  g_gemm<128, false, false><<<768, 256, 0, stream>>>(P.hb0, P.wp + WP_S1, P.bself[1],
      P.wp + WP_E1, P.bedge[1], P.degp, nullptr, P.hs, P.mmp, 768);
  g_spmm<<<512, 256, 0, stream>>>(P.bm, P.mmp, P.part);
  g_bnstat<true><<<512, 64, 0, stream>>>(P.hs, P.part, P.bng[1], P.bnb[1], P.hb1);

  // layer 2 (K=128)
  g_gemm<128, false, false><<<768, 256, 0, stream>>>(P.hb1, P.wp + WP_S2, P.bself[2],
      P.wp + WP_E2, P.bedge[2], P.degp, nullptr, P.hs, P.mmp, 768);
  g_spmm<<<512, 256, 0, stream>>>(P.bm, P.mmp, P.part);
  g_bnstat<true><<<512, 64, 0, stream>>>(P.hs, P.part, P.bng[2], P.bnb[2], P.hb0);

  // head: w1 -> BN -> relu -> w2 (self-only: 256 blocks, pr==0 path)
  g_gemm<128, false, false><<<256, 256, 0, stream>>>(P.hb0, P.wp + WP_W1, P.b1,
      nullptr, nullptr, P.degp, nullptr, P.hs, nullptr, 256);
  g_bnstat<false><<<512, 64, 0, stream>>>(P.hs, nullptr, P.bnfg, P.bnfb, P.hb1);
  g_gemm<128, false, true><<<256, 256, 0, stream>>>(P.hb1, P.wp + WP_W2, P.b2,
      nullptr, nullptr, P.degp, P.out, nullptr, nullptr, 256);
}

// Round 14
// 344.489 us; speedup vs baseline: 1.0170x; 1.0170x over previous
//
#include <hip/hip_runtime.h>
#include <stdint.h>

// RGCN round 23: REVERT to r21 champion (341.9us) byte-for-byte. r22's
// edge-quad merge regressed (+8.4us): it serialized 8 half-tile phases
// behind 7 barrier+vmcnt waits inside one block while cutting grid TLP
// 1280->768 -- merges only pay when they DELETE duplicated work without
// lengthening the per-block serial chain (r21 oc-merge did; r22 didn't).
// Session ledger: ring-spmm -13.6, gemm-pairing -3.1, wave-bnstat -1.4,
// oc-merge -4.6; traffic cuts ~0 (L3-resident), launch-cuts +9, quad +8.4.
// This locks the champion structure: 13 launches, paired gemm, oc-merged
// ring spmm, single-wave bnstat, hs bf16.

typedef float  f32x4  __attribute__((ext_vector_type(4)));
typedef __bf16 bf16x8 __attribute__((ext_vector_type(8)));
typedef __bf16 bf16x4 __attribute__((ext_vector_type(4)));
typedef unsigned short ushort8v __attribute__((ext_vector_type(8)));
typedef uint32_t uint4v __attribute__((ext_vector_type(4)));

#define MBATCH 32
#define ETYPES 4
#define NNODE  512
#define HIDD   128

#define GLB(p) (const __attribute__((address_space(1))) uint32_t*)(p)
#define LDSp(p) (__attribute__((address_space(3))) uint32_t*)(p)

// packed-weight pool offsets (elements)
#define WP_S0 0
#define WP_E0 8192
#define WP_S1 40960
#define WP_E1 57344
#define WP_S2 122880
#define WP_E2 139264
#define WP_W1 204800
#define WP_W2 221184

struct Params {
  const float* x;
  const float* adj;
  const float* wself[3]; const float* bself[3];
  const float* wedge[3]; const float* bedge[3];
  const float* bng[3];   const float* bnb[3];
  const float* w1; const float* b1;
  const float* bnfg; const float* bnfb;
  const float* w2; const float* b2;
  __bf16* mmp; __bf16* hs; __bf16* part;
  __bf16* hb0; __bf16* hb1;
  uint32_t* bm; float* degp; __bf16* wp;
  float* out;
};

// ---------------- phase: pack (r9-proven ballot body) ----------------
__device__ void pack_phase(const float* __restrict__ adj, uint32_t* __restrict__ bm,
                           float* __restrict__ degp, int bid, int t, int nbl) {
  int wave = t >> 6, lane = t & 63;
  for (int rg = bid; rg < 16384; rg += nbl) {
    int r = rg * 4 + wave;                  // 65536 rows (b,e,n)
    int b = r >> 11, e = (r >> 9) & 3, n = r & 511;
    const float* row = adj + (long)r * 512;
    uint32_t myw = 0;
#pragma unroll
    for (int i = 0; i < 8; ++i) {
      uint64_t bal = __ballot(row[i * 64 + lane] != 0.f);
      uint32_t lo = (uint32_t)bal, hi = (uint32_t)(bal >> 32);
      if ((lane >> 1) == i) myw = (lane & 1) ? hi : lo;
    }
    if (lane == (n >> 5)) myw &= ~(1u << (n & 31));   // zero diagonal
    int pc = (lane < 16) ? __popc(myw) : 0;
    pc += __shfl_down(pc, 8);
    pc += __shfl_down(pc, 4);
    pc += __shfl_down(pc, 2);
    pc += __shfl_down(pc, 1);
    if (lane < 16) bm[(long)r * 16 + lane] = myw;
    if (lane == 0) degp[e * 16384 + b * 512 + n] = (float)pc;
  }
}

// ---------------- phase: prep (r9-proven body) ----------------
__device__ void prep_phase(const Params& P, int bid, int t, int nbl) {
  const float* Ws[8] = {P.wself[0], P.wedge[0], P.wself[1], P.wedge[1],
                        P.wself[2], P.wedge[2], P.w1, P.w2};
  const int Kt[8]  = {64, 64, 128, 128, 128, 128, 128, 128};
  const int NB[8]  = {2, 8, 2, 8, 2, 8, 2, 2};
  const int OFF[8] = {WP_S0, WP_E0, WP_S1, WP_E1, WP_S2, WP_E2, WP_W1, WP_W2};
#pragma unroll
  for (int wid = 0; wid < 8; ++wid) {
    int K = Kt[wid], nblk = NB[wid];
    int tot = K * nblk * 64;
    for (int gid = bid * 256 + t; gid < tot; gid += nbl * 256) {
      int c = gid & 63;
      int k = (gid >> 6) % K;
      int blk = (gid >> 6) / K;
      int edge = (nblk == 8);
      int WS = edge ? 512 : 128;
      int col = edge ? (((blk & 1) * 64 + c) * 4 + (blk >> 1)) : (blk * 64 + c);
      P.wp[OFF[wid] + (long)blk * K * 64 + (k >> 3) * 512 + c * 8 + (k & 7)] =
          (__bf16)Ws[wid][k * WS + col];
    }
  }
}

// ---------------- phase: gemm (r19: by-pair per block, W dbuf, counted vmcnt) ----
// pair pr covers by1=2pr, by2=2pr+1 for one g0. pr==0: both self (c0 0/64);
// pr>=1: both edge, same e=pr-1, o0 0/64. H staged once per pair.
template <int K, bool F32IN, bool F32OUT>
__device__ void gemm_phase(char* smem, const void* __restrict__ hv,
                           const __bf16* __restrict__ wp_self,
                           const float* __restrict__ bias_self,
                           const __bf16* __restrict__ wp_edge,
                           const float* __restrict__ bias_edge,
                           const float* __restrict__ degp,
                           float* __restrict__ outF, __bf16* __restrict__ outB,
                           __bf16* __restrict__ mmp,
                           int npairs, int bid, int t, int nbl) {
  __bf16 (*Hl)[K + 8] = (__bf16(*)[K + 8])smem;
  __bf16* Wl0 = (__bf16*)(smem + 64 * (K + 8) * 2);   // k-packed [K/8][64][8]
  __bf16* Wl1 = Wl0 + K * 64;
  constexpr int HI = K / 32;           // H chunks per thread
  int wave = t >> 6, lane = t & 63, l15 = lane & 15, q = lane >> 4;
  for (int pairi = bid; pairi < npairs; pairi += nbl) {
    __syncthreads();                   // smem free from prev pair
    int g0 = (pairi & 255) * 64;
    int pr = pairi >> 8;
    // --- H loads first (vmcnt retires in issue order: keeps W countable) ---
    f32x4 ha[F32IN ? HI : 1], hb4[F32IN ? HI : 1];
    bf16x8 hr[F32IN ? 1 : HI];
#pragma unroll
    for (int ii = 0; ii < HI; ++ii) {
      int idx = t + ii * 256;
      int r = idx / (K / 8), ch = idx % (K / 8);
      if (F32IN) {
        const float* xf = (const float*)hv;
        ha[ii]  = *(const f32x4*)(xf + (long)(g0 + r) * K + ch * 8);
        hb4[ii] = *(const f32x4*)(xf + (long)(g0 + r) * K + ch * 8 + 4);
      } else {
        const __bf16* hbp = (const __bf16*)hv;
        hr[ii] = *(const bf16x8*)(hbp + (long)(g0 + r) * K + ch * 8);
      }
    }
    __builtin_amdgcn_sched_barrier(0);
    // --- issue W1 then W2 (K/32 gload_lds each per wave) ---
    {
      const __bf16* wb1 = (pr >= 1) ? (wp_edge + (long)(pr * 2 - 2) * K * 64)
                                    : wp_self;
      const __bf16* wb2 = (pr >= 1) ? (wp_edge + (long)(pr * 2 - 1) * K * 64)
                                    : (wp_self + (long)K * 64);
      const char* g1 = (const char*)wb1;
      const char* g2 = (const char*)wb2;
#pragma unroll
      for (int i = 0; i < K / 32; ++i)
        __builtin_amdgcn_global_load_lds(GLB(g1 + i * 4096 + wave * 1024 + lane * 16),
                                         LDSp((char*)Wl0 + i * 4096 + wave * 1024),
                                         16, 0, 0);
#pragma unroll
      for (int i = 0; i < K / 32; ++i)
        __builtin_amdgcn_global_load_lds(GLB(g2 + i * 4096 + wave * 1024 + lane * 16),
                                         LDSp((char*)Wl1 + i * 4096 + wave * 1024),
                                         16, 0, 0);
    }
    __builtin_amdgcn_sched_barrier(0);
    // --- H -> LDS (compiler waits H loads at vmcnt>=2*K/32: W stays in flight) ---
#pragma unroll
    for (int ii = 0; ii < HI; ++ii) {
      int idx = t + ii * 256;
      int r = idx / (K / 8), ch = idx % (K / 8);
      if (F32IN) {
        bf16x8 o;
#pragma unroll
        for (int j = 0; j < 4; ++j) { o[j] = (__bf16)ha[ii][j]; o[4 + j] = (__bf16)hb4[ii][j]; }
        *(bf16x8*)&Hl[r][ch * 8] = o;
      } else {
        *(bf16x8*)&Hl[r][ch * 8] = hr[ii];
      }
    }
    asm volatile("s_waitcnt lgkmcnt(0)" ::: "memory");   // H in LDS
    if (K == 128) asm volatile("s_waitcnt vmcnt(4)" ::: "memory");  // W1 done
    else          asm volatile("s_waitcnt vmcnt(2)" ::: "memory");
    __builtin_amdgcn_s_barrier();
    asm volatile("" ::: "memory");
    // --- MFMA tile 1 (Wl0) ---
    f32x4 acc1[4] = {}, acc2[4] = {};
#pragma unroll
    for (int kk = 0; kk < K / 32; ++kk) {
      bf16x8 af = *(const bf16x8*)&Hl[wave * 16 + l15][kk * 32 + q * 8];
#pragma unroll
      for (int c = 0; c < 4; ++c) {
        bf16x8 bfr = *(const bf16x8*)&Wl0[((kk * 4 + q) * 64 + c * 16 + l15) * 8];
        acc1[c] = __builtin_amdgcn_mfma_f32_16x16x32_bf16(af, bfr, acc1[c], 0, 0, 0);
      }
    }
    asm volatile("s_waitcnt vmcnt(0)" ::: "memory");     // W2 done (no stores yet)
    __builtin_amdgcn_s_barrier();
    asm volatile("" ::: "memory");
    // --- MFMA tile 2 (Wl1) ---
#pragma unroll
    for (int kk = 0; kk < K / 32; ++kk) {
      bf16x8 af = *(const bf16x8*)&Hl[wave * 16 + l15][kk * 32 + q * 8];
#pragma unroll
      for (int c = 0; c < 4; ++c) {
        bf16x8 bfr = *(const bf16x8*)&Wl1[((kk * 4 + q) * 64 + c * 16 + l15) * 8];
        acc2[c] = __builtin_amdgcn_mfma_f32_16x16x32_bf16(af, bfr, acc2[c], 0, 0, 0);
      }
    }
    // --- epilogues ---
    if (pr == 0) {                      // two self tiles: c0 = 0 and 64
#pragma unroll
      for (int h = 0; h < 2; ++h) {
        f32x4* acc = h ? acc2 : acc1;
        int c0 = h * 64;
#pragma unroll
        for (int c = 0; c < 4; ++c) {
          float bc = bias_self[c0 + c * 16 + l15];
#pragma unroll
          for (int i = 0; i < 4; ++i) {
            int g = g0 + wave * 16 + q * 4 + i;
            if (F32OUT)
              outF[(long)g * HIDD + c0 + c * 16 + l15] = acc[c][i] + bc;
            else
              outB[(long)g * HIDD + c0 + c * 16 + l15] = (__bf16)(acc[c][i] + bc);
          }
        }
      }
    } else {                            // two edge tiles: same e, o0 = 0 and 64
      int e = pr - 1;
      float iv[4];
#pragma unroll
      for (int i = 0; i < 4; ++i) {
        int gg = g0 + wave * 16 + q * 4 + i;
        float d = degp[gg] + degp[16384 + gg] + degp[32768 + gg] + degp[49152 + gg];
        iv[i] = d > 0.f ? 1.f / d : 0.f;       // bit-identical to k_inv
      }
      int b4e  = (g0 >> 9) * 4 + e;
      int octg = ((g0 & 511) >> 3) + wave * 2 + (q >> 1);
      int j0   = (q & 1) * 4;
#pragma unroll
      for (int h = 0; h < 2; ++h) {
        f32x4* acc = h ? acc2 : acc1;
        int o0 = h * 64;
#pragma unroll
        for (int c = 0; c < 4; ++c) {
          int o = o0 + c * 16 + l15;
          float bc = bias_edge[o * 4 + e];
          bf16x4 v4;
#pragma unroll
          for (int i = 0; i < 4; ++i) v4[i] = (__bf16)((acc[c][i] + bc) * iv[i]);
          *(bf16x4*)(mmp + ((long)(b4e * 64 + octg) * HIDD + o) * 8 + j0) = v4;
        }
      }
    }
  }
}

// ---------------- phase: spmm (r21: oc-merged, full-width chunks) ----------------
// grid = 512 exactly: bid -> (nt 0..3, eb = e*32+b). 8 phases (mc 0..7),
// ring of 4 x 16KB LDS buffers, 4 gload_lds per wave per phase (full 128-col
// chunk). vmcnt: 4 loads/stage, 3 stages in flight -> wait vmcnt(8) for
// mc<=5, (4) at 6, (0) at 7. Both o-halves computed: acc[8], 32 MFMA/wave/
// phase. bm masks loaded once per (e,b,nt).
__device__ void spmm_phase(char* smem, const uint32_t* __restrict__ bm,
                           const __bf16* __restrict__ mmp,
                           __bf16* __restrict__ part, int bid, int t) {
  int wave = t >> 6, lane = t & 63, l15 = lane & 15, q = lane >> 4;
  int nt = bid >> 7;                    // 0..3
  int eb = bid & 127;                   // e*32 + b
  int e = eb >> 5, b = eb & 31;
  int n0 = nt * 128;

  const uint32_t* bmr = bm + ((long)((b * 4 + e) * 512 + n0 + wave * 32 + l15)) * 16;
  uint32_t rm0[16], rm1[16];
#pragma unroll
  for (int i = 0; i < 4; ++i) {
    uint4v v0 = *(const uint4v*)(bmr + i * 4);
    uint4v v1 = *(const uint4v*)(bmr + 256 + i * 4);   // +16 rows * 16 words
    rm0[i * 4 + 0] = v0.x; rm0[i * 4 + 1] = v0.y; rm0[i * 4 + 2] = v0.z; rm0[i * 4 + 3] = v0.w;
    rm1[i * 4 + 0] = v1.x; rm1[i * 4 + 1] = v1.y; rm1[i * 4 + 2] = v1.z; rm1[i * 4 + 3] = v1.w;
  }

  // per-wave stage of phase mc: 2 octets x 2 halves (1 KB each), linear dest
  auto stage = [&](int mc, char* dst) {
#pragma unroll
    for (int i = 0; i < 2; ++i) {
      int oct = wave * 2 + i;
#pragma unroll
      for (int hf = 0; hf < 2; ++hf) {
        const char* g = (const char*)mmp +
            ((long)(b * 4 + e) * 65536 + mc * 8192 + oct * 1024 + hf * 512) * 2;
        __builtin_amdgcn_global_load_lds(GLB(g + lane * 16),
                                         LDSp(dst + oct * 2048 + hf * 1024), 16, 0, 0);
      }
    }
  };

  stage(0, smem);                      // prologue: 3 phases in flight (12 loads)
  stage(1, smem + 16384);
  stage(2, smem + 32768);

  f32x4 acc0[8] = {}, acc1[8] = {};
#pragma unroll
  for (int mc = 0; mc < 8; ++mc) {
    // wait for phase mc's 4 loads (oldest); leave later phases in flight
    if (mc <= 5)      asm volatile("s_waitcnt vmcnt(8)" ::: "memory");
    else if (mc == 6) asm volatile("s_waitcnt vmcnt(4)" ::: "memory");
    else              asm volatile("s_waitcnt vmcnt(0)" ::: "memory");
    __builtin_amdgcn_s_barrier();
    asm volatile("" ::: "memory");
    if (mc < 5) stage(mc + 3, smem + ((mc + 3) & 3) * 16384);
    const __bf16* Bl = (const __bf16*)(smem + (mc & 3) * 16384);
#pragma unroll
    for (int kk = 0; kk < 2; ++kk) {
      uint32_t bits0 = (rm0[mc * 2 + kk] >> (q * 8)) & 0xffu;
      uint32_t bits1 = (rm1[mc * 2 + kk] >> (q * 8)) & 0xffu;
      ushort8v a0, a1;
#pragma unroll
      for (int j = 0; j < 8; ++j) {
        a0[j] = (bits0 >> j & 1u) ? (unsigned short)0x3F80 : (unsigned short)0;
        a1[j] = (bits1 >> j & 1u) ? (unsigned short)0x3F80 : (unsigned short)0;
      }
      union { ushort8v u; bf16x8 v; } c0, c1; c0.u = a0; c1.u = a1;
#pragma unroll
      for (int c = 0; c < 8; ++c) {
        bf16x8 bfr = *(const bf16x8*)&Bl[((kk * 4 + q) * 128 + c * 16 + l15) * 8];
        acc0[c] = __builtin_amdgcn_mfma_f32_16x16x32_bf16(c0.v, bfr, acc0[c], 0, 0, 0);
        acc1[c] = __builtin_amdgcn_mfma_f32_16x16x32_bf16(c1.v, bfr, acc1[c], 0, 0, 0);
      }
    }
  }

  __bf16* dst = part + (long)(e * 32 + b) * NNODE * HIDD;
#pragma unroll
  for (int c = 0; c < 8; ++c) {
#pragma unroll
    for (int i = 0; i < 4; ++i) {
      int n = n0 + wave * 32 + q * 4 + i;
      int o = c * 16 + l15;
      dst[(long)n * HIDD + o] = (__bf16)acc0[c][i];
      dst[(long)(n + 16) * HIDD + o] = (__bf16)acc1[c][i];
    }
  }
}

// ---------------- phase: bnstat (r20-proven: one wave per n, barrier-free) --------
template <bool HASP>
__global__ __launch_bounds__(64) void g_bnstat(const __bf16* __restrict__ hs,
                                               const __bf16* __restrict__ part,
                                               const float* __restrict__ gg,
                                               const float* __restrict__ bb,
                                               __bf16* __restrict__ hb) {
  int n = blockIdx.x;                  // one n per wave
  int lane = threadIdx.x;
  int o4 = lane & 31;                  // o-chunk index (4 elems)
  int bq = lane >> 5;                  // 0/1
  f32x4 v[16];
  float s = 0.f, sq = 0.f;
#pragma unroll
  for (int i = 0; i < 16; ++i) {
    int b = bq + i * 2;
    long base = ((long)b * NNODE + n) * HIDD + o4 * 4;
    bf16x4 hv = *(const bf16x4*)(hs + base);
    f32x4 t;
#pragma unroll
    for (int j = 0; j < 4; ++j) t[j] = (float)hv[j];
    if (HASP) {
#pragma unroll
      for (int e = 0; e < 4; ++e) {
        bf16x4 pv = *(const bf16x4*)(part + ((long)(e * 32 + b) * NNODE + n) * HIDD + o4 * 4);
#pragma unroll
        for (int j = 0; j < 4; ++j) t[j] += (float)pv[j];
      }
    }
    v[i] = t;
#pragma unroll
    for (int j = 0; j < 4; ++j) { s += t[j]; sq += t[j] * t[j]; }
  }
#pragma unroll
  for (int off = 1; off < 64; off <<= 1) {
    s  += __shfl_xor(s, off);
    sq += __shfl_xor(sq, off);
  }
  float mean = s * (1.f / 4096.f);
  float var = sq * (1.f / 4096.f) - mean * mean;   // biased, torch BN1d
  float rstd = rsqrtf(var + 1e-5f);
  float sc = gg[n] * rstd;
  float sh = bb[n] - mean * sc;
#pragma unroll
  for (int i = 0; i < 16; ++i) {
    int b = bq + i * 2;
    bf16x4 o;
#pragma unroll
    for (int j = 0; j < 4; ++j) {
      float x = v[i][j] * sc + sh;
      o[j] = (__bf16)(x > 0.f ? x : 0.f);
    }
    *(bf16x4*)(hb + ((long)b * NNODE + n) * HIDD + o4 * 4) = o;
  }
}

// ---------------- kernels ----------------
__global__ __launch_bounds__(256) void g_packprep(Params P) {
  pack_phase(P.adj, P.bm, P.degp, blockIdx.x, threadIdx.x, gridDim.x);
  prep_phase(P, blockIdx.x, threadIdx.x, gridDim.x);
}
template <int K, bool F32IN, bool F32OUT>
__global__ __launch_bounds__(256) void g_gemm(const void* hv, const __bf16* wps,
                                              const float* bs, const __bf16* wpe,
                                              const float* be, const float* degp,
                                              float* outF, __bf16* outB,
                                              __bf16* mmp, int npairs) {
  __shared__ __align__(16) char smem[64 * (K + 8) * 2 + 2 * K * 64 * 2];
  gemm_phase<K, F32IN, F32OUT>(smem, hv, wps, bs, wpe, be, degp, outF, outB,
                               mmp, npairs, blockIdx.x, threadIdx.x, gridDim.x);
}
__global__ __launch_bounds__(256) void g_spmm(const uint32_t* bm, const __bf16* mmp,
                                              __bf16* part) {
  __shared__ __align__(16) char smem[65536];
  spmm_phase(smem, bm, mmp, part, blockIdx.x, threadIdx.x);
}

extern "C" void kernel_launch(void* const* d_in, const int* in_sizes, int n_in,
                              void* d_out, int out_size, void* d_ws, size_t ws_size,
                              hipStream_t stream) {
  (void)in_sizes; (void)n_in; (void)out_size; (void)ws_size;
  Params P;
  P.x   = (const float*)d_in[0];
  P.adj = (const float*)d_in[1];
  for (int l = 0; l < 3; ++l) {
    P.wself[l] = (const float*)d_in[2 + 6 * l];
    P.bself[l] = (const float*)d_in[3 + 6 * l];
    P.wedge[l] = (const float*)d_in[4 + 6 * l];
    P.bedge[l] = (const float*)d_in[5 + 6 * l];
    P.bng[l]   = (const float*)d_in[6 + 6 * l];
    P.bnb[l]   = (const float*)d_in[7 + 6 * l];
  }
  P.w1   = (const float*)d_in[20];
  P.b1   = (const float*)d_in[21];
  P.bnfg = (const float*)d_in[22];
  P.bnfb = (const float*)d_in[23];
  P.w2   = (const float*)d_in[24];
  P.b2   = (const float*)d_in[25];

  char* ws = (char*)d_ws;
  P.mmp  = (__bf16*)ws;                  // 16,777,216
  P.hs   = (__bf16*)(ws + 16777216);     //  4,194,304 used (slot 8 MB, bf16)
  P.part = (__bf16*)(ws + 25165824);     // 16,777,216 (bf16)
  P.hb0  = (__bf16*)(ws + 41943040);     //  4,194,304
  P.hb1  = (__bf16*)(ws + 46137344);     //  4,194,304
  P.bm   = (uint32_t*)(ws + 50331648);   //  4,194,304
  P.degp = (float*)(ws + 54525952);      //    262,144
  P.wp   = (__bf16*)(ws + 54788096);     //    475,136 -> ~55.3 MB total
  P.out  = (float*)d_out;

  g_packprep<<<16384, 256, 0, stream>>>(P);

  // layer 0 (K=64, fp32 input x): 1280 by-pairs
  g_gemm<64, true, false><<<1280, 256, 0, stream>>>(P.x, P.wp + WP_S0, P.bself[0],
      P.wp + WP_E0, P.bedge[0], P.degp, nullptr, P.hs, P.mmp, 1280);
  g_spmm<<<512, 256, 0, stream>>>(P.bm, P.mmp, P.part);
  g_bnstat<true><<<512, 64, 0, stream>>>(P.hs, P.part, P.bng[0], P.bnb[0], P.hb0);

  // layer 1 (K=128)
  g_gemm<128, false, false><<<1280, 256, 0, stream>>>(P.hb0, P.wp + WP_S1, P.bself[1],
      P.wp + WP_E1, P.bedge[1], P.degp, nullptr, P.hs, P.mmp, 1280);
  g_spmm<<<512, 256, 0, stream>>>(P.bm, P.mmp, P.part);
  g_bnstat<true><<<512, 64, 0, stream>>>(P.hs, P.part, P.bng[1], P.bnb[1], P.hb1);

  // layer 2 (K=128)
  g_gemm<128, false, false><<<1280, 256, 0, stream>>>(P.hb1, P.wp + WP_S2, P.bself[2],
      P.wp + WP_E2, P.bedge[2], P.degp, nullptr, P.hs, P.mmp, 1280);
  g_spmm<<<512, 256, 0, stream>>>(P.bm, P.mmp, P.part);
  g_bnstat<true><<<512, 64, 0, stream>>>(P.hs, P.part, P.bng[2], P.bnb[2], P.hb0);

  // head: w1 -> BN -> relu -> w2 (pairs: 256 each, self-only)
  g_gemm<128, false, false><<<256, 256, 0, stream>>>(P.hb0, P.wp + WP_W1, P.b1,
      nullptr, nullptr, P.degp, nullptr, P.hs, nullptr, 256);
  g_bnstat<false><<<512, 64, 0, stream>>>(P.hs, nullptr, P.bnfg, P.bnfb, P.hb1);
  g_gemm<128, false, true><<<256, 256, 0, stream>>>(P.hb1, P.wp + WP_W2, P.b2,
      nullptr, nullptr, P.degp, P.out, nullptr, nullptr, 256);
}